// Round 17
// baseline (996.958 us; speedup 1.0000x reference)
//
#include <hip/hip_runtime.h>

#define DIM 1024
#define NKN 65536
#define TOK 4096
#define CK 20
#define FK 10
#define RNK 128
#define CAP 256
#define NCHUNK 512   // 65536 / 128 cols per GEMM block

typedef __bf16 v8bf __attribute__((ext_vector_type(8)));
typedef float v4f __attribute__((ext_vector_type(4)));

#define AS1 __attribute__((address_space(1)))
#define AS3 __attribute__((address_space(3)))

__device__ __forceinline__ unsigned short f2bf(float f) {
  // round-to-nearest-even fp32 -> bf16 (finite inputs only)
  unsigned u = __builtin_bit_cast(unsigned, f);
  u += 0x7FFFu + ((u >> 16) & 1u);
  return (unsigned short)(u >> 16);
}
__device__ __forceinline__ unsigned short bf2key(unsigned short b) {
  // monotone order-preserving key for bf16 bits
  return (b & 0x8000) ? (unsigned short)(~b) : (unsigned short)(b | 0x8000);
}

// ---------------------------------------------------------------------------
// K1: transpose W_router [DIM][NKN] -> WT fp32 [NKN][DIM] + WT bf16 [NKN][DIM]
// (r15 exact)
// ---------------------------------------------------------------------------
__global__ __launch_bounds__(256) void k_transpose(const float* __restrict__ W,
                                                   float* __restrict__ WT,
                                                   unsigned short* __restrict__ WTb) {
  __shared__ float tile[32][33];
  const int n0 = (blockIdx.x & 2047) << 5;
  const int d0 = (blockIdx.x >> 11) << 5;
  const int c = threadIdx.x & 31, r0 = threadIdx.x >> 5;
#pragma unroll
  for (int i = 0; i < 4; i++) {
    int r = r0 + i * 8;
    tile[r][c] = W[(size_t)(d0 + r) * NKN + n0 + c];
  }
  __syncthreads();
#pragma unroll
  for (int i = 0; i < 4; i++) {
    int r = r0 + i * 8;
    float v = tile[c][r];  // = W[d0+c][n0+r]
    size_t o = (size_t)(n0 + r) * DIM + d0 + c;
    WT[o] = v;
    WTb[o] = f2bf(v);
  }
}

// ---------------------------------------------------------------------------
// K1b: convert x fp32 -> bf16 (r15 exact)
// ---------------------------------------------------------------------------
__global__ __launch_bounds__(256) void k_cvt_x(const float* __restrict__ x,
                                               unsigned short* __restrict__ xb) {
  const int i = blockIdx.x * 256 + threadIdx.x;
  const float4 v = reinterpret_cast<const float4*>(x)[i];
  ushort4 o;
  o.x = f2bf(v.x); o.y = f2bf(v.y); o.z = f2bf(v.z); o.w = f2bf(v.w);
  reinterpret_cast<ushort4*>(xb)[i] = o;
}

// ---------------------------------------------------------------------------
// K2: bf16 MFMA GEMM + fused top-8 select epilogue (r15 exact; 920 TF,
// at the 2-phase plain-HIP structure ceiling).
// ---------------------------------------------------------------------------
__global__ __launch_bounds__(512, 4) void k_gemm(const unsigned short* __restrict__ A,
                                                 const unsigned short* __restrict__ Bt,
                                                 unsigned* __restrict__ Ttop) {
  __shared__ __align__(16) char lds[73728];  // ring[3]; epilogue: keys [256][136] u16
  const int tid = threadIdx.x;
  const int lane = tid & 63, wid = tid >> 6;
  const int wm = wid >> 1, wn = wid & 1;
  const int mb = blockIdx.x & 15, nb = blockIdx.x >> 4;  // m-fast: B-panel reuse
  const int m0 = mb << 8, n0 = nb << 7;
  const int rm = lane & 15, lq = lane >> 4;
  v4f acc[4][4] = {};

  const int u8 = (((tid & 3) ^ ((tid >> 3) & 3)) << 3);
  const unsigned short* aSrc = A + (size_t)(m0 + (tid >> 2)) * DIM + u8;
  const unsigned short* bSrc = Bt + (size_t)(n0 + (tid >> 2)) * DIM + u8;

  const int sx = ((lq ^ ((rm >> 1) & 3)) << 4);
  const int aOff = (wm * 64 + rm) * 64 + sx;           // + fr*1024
  const int bOff = 16384 + (wn * 64 + rm) * 64 + sx;   // + nf*1024

#define STAGE(SLOT, KT) do { \
    char* _b = lds + (SLOT) * 24576 + tid * 16; \
    __builtin_amdgcn_global_load_lds((const AS1 void*)(aSrc + (KT)),             (AS3 void*)(_b),         16, 0, 0); \
    __builtin_amdgcn_global_load_lds((const AS1 void*)(aSrc + (KT) + 128 * DIM), (AS3 void*)(_b + 8192),  16, 0, 0); \
    __builtin_amdgcn_global_load_lds((const AS1 void*)(bSrc + (KT)),             (AS3 void*)(_b + 16384), 16, 0, 0); \
  } while (0)

#define TILE(T, VM, DOSTAGE) do { \
    asm volatile("s_waitcnt vmcnt(" VM ")" ::: "memory"); \
    __builtin_amdgcn_s_barrier(); \
    if (DOSTAGE) STAGE(((T) + 2) % 3, ((T) + 2) * 32); \
    const char* sb = lds + ((T) % 3) * 24576; \
    v8bf a0 = *(const v8bf*)(sb + aOff); \
    v8bf a1 = *(const v8bf*)(sb + aOff + 1024); \
    v8bf a2 = *(const v8bf*)(sb + aOff + 2048); \
    v8bf a3 = *(const v8bf*)(sb + aOff + 3072); \
    v8bf b0 = *(const v8bf*)(sb + bOff); \
    v8bf b1 = *(const v8bf*)(sb + bOff + 1024); \
    v8bf b2 = *(const v8bf*)(sb + bOff + 2048); \
    v8bf b3 = *(const v8bf*)(sb + bOff + 3072); \
    __builtin_amdgcn_s_setprio(1); \
    _Pragma("unroll") for (int nf = 0; nf < 4; ++nf) { \
      v8bf bb = (nf == 0) ? b0 : (nf == 1) ? b1 : (nf == 2) ? b2 : b3; \
      acc[0][nf] = __builtin_amdgcn_mfma_f32_16x16x32_bf16(a0, bb, acc[0][nf], 0, 0, 0); \
      acc[1][nf] = __builtin_amdgcn_mfma_f32_16x16x32_bf16(a1, bb, acc[1][nf], 0, 0, 0); \
      acc[2][nf] = __builtin_amdgcn_mfma_f32_16x16x32_bf16(a2, bb, acc[2][nf], 0, 0, 0); \
      acc[3][nf] = __builtin_amdgcn_mfma_f32_16x16x32_bf16(a3, bb, acc[3][nf], 0, 0, 0); \
    } \
    __builtin_amdgcn_s_setprio(0); \
  } while (0)

  STAGE(0, 0);
  STAGE(1, 32);

  for (int t = 0; t < 30; ++t) {
    TILE(t, "3", true);
  }
  TILE(30, "3", false);
  TILE(31, "0", false);
#undef TILE
#undef STAGE

  // ---- epilogue: per-row top-8 of this block's 128 cols ----
  __syncthreads();
  unsigned short* keys = (unsigned short*)lds;  // [256][136]
#pragma unroll
  for (int fr = 0; fr < 4; ++fr) {
    const int lrow = wm * 64 + fr * 16 + lq * 4;
#pragma unroll
    for (int nf = 0; nf < 4; ++nf) {
      const int lcol = wn * 64 + nf * 16 + rm;
#pragma unroll
      for (int r = 0; r < 4; ++r)
        keys[(lrow + r) * 136 + lcol] = bf2key(f2bf(acc[fr][nf][r]));
    }
  }
  __syncthreads();
  if (tid < 256) {
    const uint4* krow = (const uint4*)((const char*)lds + tid * 272);
    unsigned s0 = 0, s1 = 0, s2 = 0, s3 = 0, s4 = 0, s5 = 0, s6 = 0, s7 = 0;
#pragma unroll 4
    for (int k = 0; k < 16; ++k) {
      const uint4 wv = krow[k];
      const unsigned base = (unsigned)(n0 + k * 8);
      const unsigned wd[4] = {wv.x, wv.y, wv.z, wv.w};
#pragma unroll
      for (int q = 0; q < 4; ++q) {
        const unsigned c0 = ((wd[q] & 0xFFFFu) << 16) | (base + 2 * q);
        const unsigned c1 = (wd[q] & 0xFFFF0000u) | (base + 2 * q + 1);
#define INS(C) \
        if ((C) > s7) { \
          s7 = (C); unsigned tswp; \
          if (s7 > s6) { tswp = s6; s6 = s7; s7 = tswp; } \
          if (s6 > s5) { tswp = s5; s5 = s6; s6 = tswp; } \
          if (s5 > s4) { tswp = s4; s4 = s5; s5 = tswp; } \
          if (s4 > s3) { tswp = s3; s3 = s4; s4 = tswp; } \
          if (s3 > s2) { tswp = s2; s2 = s3; s3 = tswp; } \
          if (s2 > s1) { tswp = s1; s1 = s2; s2 = tswp; } \
          if (s1 > s0) { tswp = s0; s0 = s1; s1 = tswp; } \
        }
        INS(c0)
        INS(c1)
#undef INS
      }
    }
    unsigned* dst = Ttop + ((size_t)(m0 + tid) * NCHUNK + nb) * 8;
    uint4 o0 = {s0, s1, s2, s3}, o1 = {s4, s5, s6, s7};
    reinterpret_cast<uint4*>(dst)[0] = o0;
    reinterpret_cast<uint4*>(dst)[1] = o1;
  }
}

// ---------------------------------------------------------------------------
// K3 (r17): 512 threads / 8 waves, 2 rows in flight per wave (16 concurrent
// row-gathers per block). pick from per-chunk top-8 table + exact fp64
// rescore + exact top-20.
// ---------------------------------------------------------------------------
__global__ __launch_bounds__(512) void k_pickscore(const unsigned* __restrict__ Ttop,
                                                   const float* __restrict__ x,
                                                   const float* __restrict__ WT,
                                                   int* __restrict__ coarse) {
  __shared__ unsigned ent[NCHUNK * 8];          // 16 KB
  __shared__ __align__(16) float xs[DIM];
  __shared__ double sc[CAP];
  __shared__ int ci[CAP];
  __shared__ int scnt, bsS;
  const int t = blockIdx.x, tid = threadIdx.x;
  const int lane = tid & 63, w = tid >> 6;
  {
    const uint4* src = reinterpret_cast<const uint4*>(Ttop + (size_t)t * NCHUNK * 8);
    for (int i = tid; i < 1024; i += 512)
      reinterpret_cast<uint4*>(ent)[i] = src[i];
    if (tid < 256)
      reinterpret_cast<float4*>(xs)[tid] =
          reinterpret_cast<const float4*>(x + (size_t)t * DIM)[tid];
  }
  if (tid == 0) scnt = 0;
  __syncthreads();
  // tau = 32nd-largest chunk-max key (entry 0 of each chunk); wave 0
  if (w == 0) {
    int v[8];
#pragma unroll
    for (int j = 0; j < 8; j++) v[j] = (int)(ent[(lane * 8 + j) * 8] >> 16);
    int t32 = 0;
    for (int it = 0; it < 32; it++) {
      int lm = v[0];
#pragma unroll
      for (int j = 1; j < 8; j++) lm = max(lm, v[j]);
      int gm = lm;
#pragma unroll
      for (int off = 32; off > 0; off >>= 1) gm = max(gm, __shfl_xor(gm, off));
      unsigned long long msk = __ballot(lm == gm);
      if (lane == __ffsll((long long)msk) - 1) {
        bool done = false;
#pragma unroll
        for (int j = 0; j < 8; j++)
          if (!done && v[j] == gm) { v[j] = -1; done = true; }
      }
      t32 = gm;
    }
    if (lane == 0) bsS = t32;
  }
  __syncthreads();
  const unsigned bs = (unsigned)bsS;
  for (int i = tid; i < NCHUNK * 8; i += 512) {
    const unsigned e = ent[i];
    if ((e >> 16) >= bs) {
      int p = atomicAdd(&scnt, 1);
      if (p < CAP) ci[p] = (int)(e & 0xFFFFu);
    }
  }
  __syncthreads();
  const int cnt = min(scnt, CAP);
  if (tid < CAP) {
    if (tid >= cnt) ci[tid] = 0;
    sc[tid] = -1e300;
  }
  __syncthreads();
  // exact fp64 rescore: 8 waves, two candidate rows per wave-iteration
  {
    const float4* xv4 = reinterpret_cast<const float4*>(xs);
    for (int c = w; c < cnt; c += 16) {
      const int c2 = c + 8;
      const bool has2 = (c2 < cnt);
      const float4* wr1 = reinterpret_cast<const float4*>(WT + (size_t)ci[c] * DIM);
      const float4* wr2 = reinterpret_cast<const float4*>(WT + (size_t)ci[has2 ? c2 : c] * DIM);
      double sa = 0.0, sb2 = 0.0;
#pragma unroll
      for (int k = 0; k < 4; k++) {
        const float4 w1 = wr1[k * 64 + lane];
        const float4 w2 = wr2[k * 64 + lane];
        const float4 xv = xv4[k * 64 + lane];
        sa  += (double)xv.x * w1.x + (double)xv.y * w1.y
             + (double)xv.z * w1.z + (double)xv.w * w1.w;
        sb2 += (double)xv.x * w2.x + (double)xv.y * w2.y
             + (double)xv.z * w2.z + (double)xv.w * w2.w;
      }
#pragma unroll
      for (int off = 32; off > 0; off >>= 1) {
        sa += __shfl_down(sa, off);
        sb2 += __shfl_down(sb2, off);
      }
      if (lane == 0) {
        sc[c] = sa;
        if (has2) sc[c2] = sb2;
      }
    }
  }
  __syncthreads();
  // exact top-20 (wave 0)
  if (w == 0) {
    double v[4];
    int ix[4];
#pragma unroll
    for (int j = 0; j < 4; j++) { v[j] = sc[lane + j * 64]; ix[j] = lane + j * 64; }
    for (int kk = 0; kk < CK; kk++) {
      double v1 = v[0]; int i1 = ix[0];
#pragma unroll
      for (int j = 1; j < 4; j++)
        if (v[j] > v1) { v1 = v[j]; i1 = ix[j]; }
#pragma unroll
      for (int off = 32; off > 0; off >>= 1) {
        double ov = __shfl_down(v1, off);
        int oi = __shfl_down(i1, off);
        if (ov > v1) { v1 = ov; i1 = oi; }
      }
      i1 = __shfl(i1, 0);
      if (lane == 0) coarse[(size_t)t * CK + kk] = ci[i1];
#pragma unroll
      for (int j = 0; j < 4; j++)
        if (i1 == ix[j]) v[j] = -1e300;
    }
  }
}

// ---------------------------------------------------------------------------
// K4a (r16 exact): query = x @ W_enc, 8 tokens/block.
// ---------------------------------------------------------------------------
__global__ __launch_bounds__(256) void k_query8(const float* __restrict__ x,
                                                const float* __restrict__ Wenc,
                                                float* __restrict__ q) {
  __shared__ __align__(16) float xs8[8 * DIM];  // 32 KB
  __shared__ float pq[2][8][RNK];               // 8 KB
  const int t0 = blockIdx.x * 8, tid = threadIdx.x;
  for (int i = tid; i < 2048; i += 256)
    reinterpret_cast<float4*>(xs8)[i] =
        reinterpret_cast<const float4*>(x + (size_t)t0 * DIM)[i];
  __syncthreads();
  const int j = tid & 127, g = tid >> 7;
  float s[8] = {0.f, 0.f, 0.f, 0.f, 0.f, 0.f, 0.f, 0.f};
  for (int d = g * 512; d < g * 512 + 512; ++d) {
    const float wv = Wenc[(size_t)d * RNK + j];
#pragma unroll
    for (int tok = 0; tok < 8; ++tok)
      s[tok] = fmaf(xs8[tok * DIM + d], wv, s[tok]);
  }
#pragma unroll
  for (int tok = 0; tok < 8; ++tok) pq[g][tok][j] = s[tok];
  __syncthreads();
  for (int i = tid; i < 8 * RNK; i += 256) {
    const int tok = i >> 7, jj = i & 127;
    q[(size_t)(t0 + tok) * RNK + jj] = pq[0][tok][jj] + pq[1][tok][jj];
  }
}

// ---------------------------------------------------------------------------
// K4b (r16 exact): fine scores vs 20 candidates, top-10, softmax, V blend.
// ---------------------------------------------------------------------------
__global__ __launch_bounds__(256) void k_fine(const float* __restrict__ q,
                                              const float* __restrict__ Kall,
                                              const float* __restrict__ Vall,
                                              const int* __restrict__ coarse,
                                              float* __restrict__ out) {
  __shared__ float qs[RNK];
  __shared__ float fsc[CK];
  __shared__ int gix[CK];
  __shared__ float wts[FK];
  __shared__ int fidx[FK];
  const int t = blockIdx.x, tid = threadIdx.x;
  const int lane = tid & 63, w = tid >> 6;
  if (tid < RNK) qs[tid] = q[(size_t)t * RNK + tid];
  if (tid < CK) gix[tid] = coarse[(size_t)t * CK + tid];
  __syncthreads();
  for (int c = w; c < CK; c += 4) {
    const float* kr = Kall + (size_t)gix[c] * RNK;
    float s = 0.f;
    s = fmaf(qs[lane], kr[lane], s);
    s = fmaf(qs[lane + 64], kr[lane + 64], s);
#pragma unroll
    for (int off = 32; off > 0; off >>= 1) s += __shfl_down(s, off);
    if (lane == 0) fsc[c] = s * 0.08838834764831843f;  // 1/sqrt(128)
  }
  __syncthreads();
  if (w == 0) {
    float vv = (lane < CK) ? fsc[lane] : -3e38f;
    float myv = -3e38f; int myp = 0;
    for (int kk = 0; kk < FK; kk++) {
      float v1 = vv; int p1 = lane;
#pragma unroll
      for (int off = 32; off > 0; off >>= 1) {
        float ov = __shfl_down(v1, off);
        int op = __shfl_down(p1, off);
        if (ov > v1) { v1 = ov; p1 = op; }
      }
      v1 = __shfl(v1, 0); p1 = __shfl(p1, 0);
      if (lane == kk) { myv = v1; myp = p1; }
      if (lane == p1) vv = -3e38f;
    }
    float sv = (lane < FK) ? myv : -3e38f;
    float mx = sv;
#pragma unroll
    for (int off = 8; off > 0; off >>= 1) mx = fmaxf(mx, __shfl_xor(mx, off, 16));
    float e = (lane < FK) ? expf(sv - mx) : 0.f;
    float se = e;
#pragma unroll
    for (int off = 8; off > 0; off >>= 1) se += __shfl_xor(se, off, 16);
    if (lane < FK) { wts[lane] = e / se; fidx[lane] = gix[myp]; }
  }
  __syncthreads();
  float4 a = make_float4(0.f, 0.f, 0.f, 0.f);
#pragma unroll
  for (int f = 0; f < FK; f++) {
    const float wt = wts[f];
    const float4 v = *reinterpret_cast<const float4*>(&Vall[(size_t)fidx[f] * DIM + tid * 4]);
    a.x = fmaf(wt, v.x, a.x);
    a.y = fmaf(wt, v.y, a.y);
    a.z = fmaf(wt, v.z, a.z);
    a.w = fmaf(wt, v.w, a.w);
  }
  *reinterpret_cast<float4*>(&out[(size_t)t * DIM + tid * 4]) = a;
}

// ---------------------------------------------------------------------------

extern "C" void kernel_launch(void* const* d_in, const int* in_sizes, int n_in,
                              void* d_out, int out_size, void* d_ws, size_t ws_size,
                              hipStream_t stream) {
  const float* x = (const float*)d_in[0];      // [4096][1024]
  const float* Wr = (const float*)d_in[1];     // [1024][65536]
  const float* Wenc = (const float*)d_in[2];   // [1024][128]
  const float* Kall = (const float*)d_in[3];   // [65536][128]
  const float* Vall = (const float*)d_in[4];   // [65536][1024]
  float* out = (float*)d_out;                  // [4096][1024]

  char* ws = (char*)d_ws;
  constexpr size_t OFF_WT = 0;                  // fp32 W^T    256 MB (live until pickscore)
  constexpr size_t OFF_WTB = 268435456;         // bf16 W^T    128 MB (dead after gemm)
  constexpr size_t OFF_XB = 402653184;          // bf16 x        8 MB (dead after gemm)
  constexpr size_t OFF_TTOP = 411041792;        // top-8 table  64 MB
  float* WT = (float*)(ws + OFF_WT);
  unsigned short* WTb = (unsigned short*)(ws + OFF_WTB);
  unsigned short* xb = (unsigned short*)(ws + OFF_XB);
  unsigned* Ttop = (unsigned*)(ws + OFF_TTOP);
  int* coarse = (int*)(ws + OFF_XB);            // 320 KB, aliases dead xb region
  float* q = (float*)(ws + OFF_XB + 4194304);   // 2 MB, aliases dead xb region

  k_transpose<<<65536, 256, 0, stream>>>(Wr, WT, WTb);
  k_cvt_x<<<4096, 256, 0, stream>>>(x, xb);
  k_gemm<<<8192, 512, 0, stream>>>(xb, WTb, Ttop);
  k_pickscore<<<4096, 512, 0, stream>>>(Ttop, x, WT, coarse);
  k_query8<<<512, 256, 0, stream>>>(x, Wenc, q);
  k_fine<<<4096, 256, 0, stream>>>(q, Kall, Vall, coarse, out);
}

// Round 18
// 967.888 us; speedup vs baseline: 1.0300x; 1.0300x over previous
//
#include <hip/hip_runtime.h>

#define DIM 1024
#define NKN 65536
#define TOK 4096
#define CK 20
#define FK 10
#define RNK 128
#define CAP 256
#define NCHUNK 512   // 65536 / 128 cols per GEMM block

typedef __bf16 v8bf __attribute__((ext_vector_type(8)));
typedef float v4f __attribute__((ext_vector_type(4)));

#define AS1 __attribute__((address_space(1)))
#define AS3 __attribute__((address_space(3)))

__device__ __forceinline__ unsigned short f2bf(float f) {
  // round-to-nearest-even fp32 -> bf16 (finite inputs only)
  unsigned u = __builtin_bit_cast(unsigned, f);
  u += 0x7FFFu + ((u >> 16) & 1u);
  return (unsigned short)(u >> 16);
}
__device__ __forceinline__ unsigned short bf2key(unsigned short b) {
  // monotone order-preserving key for bf16 bits
  return (b & 0x8000) ? (unsigned short)(~b) : (unsigned short)(b | 0x8000);
}

// ---------------------------------------------------------------------------
// K1 (r18): blocks [0,65536): transpose W_router [DIM][NKN] -> WT fp32 +
// WTb bf16 [NKN][DIM]. blocks [65536,69632): convert x fp32 -> bf16.
// (merged to save one launch; per-block-uniform branch)
// ---------------------------------------------------------------------------
__global__ __launch_bounds__(256) void k_prep(const float* __restrict__ W,
                                              float* __restrict__ WT,
                                              unsigned short* __restrict__ WTb,
                                              const float* __restrict__ x,
                                              unsigned short* __restrict__ xb) {
  if (blockIdx.x >= 65536) {
    const int i = (blockIdx.x - 65536) * 256 + threadIdx.x;
    const float4 v = reinterpret_cast<const float4*>(x)[i];
    ushort4 o;
    o.x = f2bf(v.x); o.y = f2bf(v.y); o.z = f2bf(v.z); o.w = f2bf(v.w);
    reinterpret_cast<ushort4*>(xb)[i] = o;
    return;
  }
  __shared__ float tile[32][33];
  const int n0 = (blockIdx.x & 2047) << 5;
  const int d0 = (blockIdx.x >> 11) << 5;
  const int c = threadIdx.x & 31, r0 = threadIdx.x >> 5;
#pragma unroll
  for (int i = 0; i < 4; i++) {
    int r = r0 + i * 8;
    tile[r][c] = W[(size_t)(d0 + r) * NKN + n0 + c];
  }
  __syncthreads();
#pragma unroll
  for (int i = 0; i < 4; i++) {
    int r = r0 + i * 8;
    float v = tile[c][r];  // = W[d0+c][n0+r]
    size_t o = (size_t)(n0 + r) * DIM + d0 + c;
    WT[o] = v;
    WTb[o] = f2bf(v);
  }
}

// ---------------------------------------------------------------------------
// K2: bf16 MFMA GEMM + fused top-8 select epilogue (r15 exact; 920 TF,
// at the 2-phase plain-HIP structure ceiling).
// ---------------------------------------------------------------------------
__global__ __launch_bounds__(512, 4) void k_gemm(const unsigned short* __restrict__ A,
                                                 const unsigned short* __restrict__ Bt,
                                                 unsigned* __restrict__ Ttop) {
  __shared__ __align__(16) char lds[73728];  // ring[3]; epilogue: keys [256][136] u16
  const int tid = threadIdx.x;
  const int lane = tid & 63, wid = tid >> 6;
  const int wm = wid >> 1, wn = wid & 1;
  const int mb = blockIdx.x & 15, nb = blockIdx.x >> 4;  // m-fast: B-panel reuse
  const int m0 = mb << 8, n0 = nb << 7;
  const int rm = lane & 15, lq = lane >> 4;
  v4f acc[4][4] = {};

  const int u8 = (((tid & 3) ^ ((tid >> 3) & 3)) << 3);
  const unsigned short* aSrc = A + (size_t)(m0 + (tid >> 2)) * DIM + u8;
  const unsigned short* bSrc = Bt + (size_t)(n0 + (tid >> 2)) * DIM + u8;

  const int sx = ((lq ^ ((rm >> 1) & 3)) << 4);
  const int aOff = (wm * 64 + rm) * 64 + sx;           // + fr*1024
  const int bOff = 16384 + (wn * 64 + rm) * 64 + sx;   // + nf*1024

#define STAGE(SLOT, KT) do { \
    char* _b = lds + (SLOT) * 24576 + tid * 16; \
    __builtin_amdgcn_global_load_lds((const AS1 void*)(aSrc + (KT)),             (AS3 void*)(_b),         16, 0, 0); \
    __builtin_amdgcn_global_load_lds((const AS1 void*)(aSrc + (KT) + 128 * DIM), (AS3 void*)(_b + 8192),  16, 0, 0); \
    __builtin_amdgcn_global_load_lds((const AS1 void*)(bSrc + (KT)),             (AS3 void*)(_b + 16384), 16, 0, 0); \
  } while (0)

#define TILE(T, VM, DOSTAGE) do { \
    asm volatile("s_waitcnt vmcnt(" VM ")" ::: "memory"); \
    __builtin_amdgcn_s_barrier(); \
    if (DOSTAGE) STAGE(((T) + 2) % 3, ((T) + 2) * 32); \
    const char* sb = lds + ((T) % 3) * 24576; \
    v8bf a0 = *(const v8bf*)(sb + aOff); \
    v8bf a1 = *(const v8bf*)(sb + aOff + 1024); \
    v8bf a2 = *(const v8bf*)(sb + aOff + 2048); \
    v8bf a3 = *(const v8bf*)(sb + aOff + 3072); \
    v8bf b0 = *(const v8bf*)(sb + bOff); \
    v8bf b1 = *(const v8bf*)(sb + bOff + 1024); \
    v8bf b2 = *(const v8bf*)(sb + bOff + 2048); \
    v8bf b3 = *(const v8bf*)(sb + bOff + 3072); \
    __builtin_amdgcn_s_setprio(1); \
    _Pragma("unroll") for (int nf = 0; nf < 4; ++nf) { \
      v8bf bb = (nf == 0) ? b0 : (nf == 1) ? b1 : (nf == 2) ? b2 : b3; \
      acc[0][nf] = __builtin_amdgcn_mfma_f32_16x16x32_bf16(a0, bb, acc[0][nf], 0, 0, 0); \
      acc[1][nf] = __builtin_amdgcn_mfma_f32_16x16x32_bf16(a1, bb, acc[1][nf], 0, 0, 0); \
      acc[2][nf] = __builtin_amdgcn_mfma_f32_16x16x32_bf16(a2, bb, acc[2][nf], 0, 0, 0); \
      acc[3][nf] = __builtin_amdgcn_mfma_f32_16x16x32_bf16(a3, bb, acc[3][nf], 0, 0, 0); \
    } \
    __builtin_amdgcn_s_setprio(0); \
  } while (0)

  STAGE(0, 0);
  STAGE(1, 32);

  for (int t = 0; t < 30; ++t) {
    TILE(t, "3", true);
  }
  TILE(30, "3", false);
  TILE(31, "0", false);
#undef TILE
#undef STAGE

  // ---- epilogue: per-row top-8 of this block's 128 cols ----
  __syncthreads();
  unsigned short* keys = (unsigned short*)lds;  // [256][136]
#pragma unroll
  for (int fr = 0; fr < 4; ++fr) {
    const int lrow = wm * 64 + fr * 16 + lq * 4;
#pragma unroll
    for (int nf = 0; nf < 4; ++nf) {
      const int lcol = wn * 64 + nf * 16 + rm;
#pragma unroll
      for (int r = 0; r < 4; ++r)
        keys[(lrow + r) * 136 + lcol] = bf2key(f2bf(acc[fr][nf][r]));
    }
  }
  __syncthreads();
  if (tid < 256) {
    const uint4* krow = (const uint4*)((const char*)lds + tid * 272);
    unsigned s0 = 0, s1 = 0, s2 = 0, s3 = 0, s4 = 0, s5 = 0, s6 = 0, s7 = 0;
#pragma unroll 4
    for (int k = 0; k < 16; ++k) {
      const uint4 wv = krow[k];
      const unsigned base = (unsigned)(n0 + k * 8);
      const unsigned wd[4] = {wv.x, wv.y, wv.z, wv.w};
#pragma unroll
      for (int q = 0; q < 4; ++q) {
        const unsigned c0 = ((wd[q] & 0xFFFFu) << 16) | (base + 2 * q);
        const unsigned c1 = (wd[q] & 0xFFFF0000u) | (base + 2 * q + 1);
#define INS(C) \
        if ((C) > s7) { \
          s7 = (C); unsigned tswp; \
          if (s7 > s6) { tswp = s6; s6 = s7; s7 = tswp; } \
          if (s6 > s5) { tswp = s5; s5 = s6; s6 = tswp; } \
          if (s5 > s4) { tswp = s4; s4 = s5; s5 = tswp; } \
          if (s4 > s3) { tswp = s3; s3 = s4; s4 = tswp; } \
          if (s3 > s2) { tswp = s2; s2 = s3; s3 = tswp; } \
          if (s2 > s1) { tswp = s1; s1 = s2; s2 = tswp; } \
          if (s1 > s0) { tswp = s0; s0 = s1; s1 = tswp; } \
        }
        INS(c0)
        INS(c1)
#undef INS
      }
    }
    unsigned* dst = Ttop + ((size_t)(m0 + tid) * NCHUNK + nb) * 8;
    uint4 o0 = {s0, s1, s2, s3}, o1 = {s4, s5, s6, s7};
    reinterpret_cast<uint4*>(dst)[0] = o0;
    reinterpret_cast<uint4*>(dst)[1] = o1;
  }
}

// ---------------------------------------------------------------------------
// K3 (r16 exact, 256 threads): pick from per-chunk top-8 table + exact fp64
// rescore (2-way MLP) + exact top-20.
// ---------------------------------------------------------------------------
__global__ __launch_bounds__(256) void k_pickscore(const unsigned* __restrict__ Ttop,
                                                   const float* __restrict__ x,
                                                   const float* __restrict__ WT,
                                                   int* __restrict__ coarse) {
  __shared__ unsigned ent[NCHUNK * 8];          // 16 KB
  __shared__ __align__(16) float xs[DIM];
  __shared__ double sc[CAP];
  __shared__ int ci[CAP];
  __shared__ int scnt, bsS;
  const int t = blockIdx.x, tid = threadIdx.x;
  const int lane = tid & 63, w = tid >> 6;
  {
    const uint4* src = reinterpret_cast<const uint4*>(Ttop + (size_t)t * NCHUNK * 8);
    for (int i = tid; i < 1024; i += 256)
      reinterpret_cast<uint4*>(ent)[i] = src[i];
    reinterpret_cast<float4*>(xs)[tid] =
        reinterpret_cast<const float4*>(x + (size_t)t * DIM)[tid];
  }
  if (tid == 0) scnt = 0;
  __syncthreads();
  // tau = 32nd-largest chunk-max key (entry 0 of each chunk); wave 0
  if (w == 0) {
    int v[8];
#pragma unroll
    for (int j = 0; j < 8; j++) v[j] = (int)(ent[(lane * 8 + j) * 8] >> 16);
    int t32 = 0;
    for (int it = 0; it < 32; it++) {
      int lm = v[0];
#pragma unroll
      for (int j = 1; j < 8; j++) lm = max(lm, v[j]);
      int gm = lm;
#pragma unroll
      for (int off = 32; off > 0; off >>= 1) gm = max(gm, __shfl_xor(gm, off));
      unsigned long long msk = __ballot(lm == gm);
      if (lane == __ffsll((long long)msk) - 1) {
        bool done = false;
#pragma unroll
        for (int j = 0; j < 8; j++)
          if (!done && v[j] == gm) { v[j] = -1; done = true; }
      }
      t32 = gm;
    }
    if (lane == 0) bsS = t32;
  }
  __syncthreads();
  const unsigned bs = (unsigned)bsS;
  for (int i = tid; i < NCHUNK * 8; i += 256) {
    const unsigned e = ent[i];
    if ((e >> 16) >= bs) {
      int p = atomicAdd(&scnt, 1);
      if (p < CAP) ci[p] = (int)(e & 0xFFFFu);
    }
  }
  __syncthreads();
  const int cnt = min(scnt, CAP);
  if (tid < CAP) {
    if (tid >= cnt) ci[tid] = 0;
    sc[tid] = -1e300;
  }
  __syncthreads();
  // exact fp64 rescore: 4 waves, TWO candidate rows per wave-iteration
  {
    const float4* xv4 = reinterpret_cast<const float4*>(xs);
    for (int c = w; c < cnt; c += 8) {
      const int c2 = c + 4;
      const bool has2 = (c2 < cnt);
      const float4* wr1 = reinterpret_cast<const float4*>(WT + (size_t)ci[c] * DIM);
      const float4* wr2 = reinterpret_cast<const float4*>(WT + (size_t)ci[has2 ? c2 : c] * DIM);
      double sa = 0.0, sb2 = 0.0;
#pragma unroll
      for (int k = 0; k < 4; k++) {
        const float4 w1 = wr1[k * 64 + lane];
        const float4 w2 = wr2[k * 64 + lane];
        const float4 xv = xv4[k * 64 + lane];
        sa  += (double)xv.x * w1.x + (double)xv.y * w1.y
             + (double)xv.z * w1.z + (double)xv.w * w1.w;
        sb2 += (double)xv.x * w2.x + (double)xv.y * w2.y
             + (double)xv.z * w2.z + (double)xv.w * w2.w;
      }
#pragma unroll
      for (int off = 32; off > 0; off >>= 1) {
        sa += __shfl_down(sa, off);
        sb2 += __shfl_down(sb2, off);
      }
      if (lane == 0) {
        sc[c] = sa;
        if (has2) sc[c2] = sb2;
      }
    }
  }
  __syncthreads();
  // exact top-20 (wave 0)
  if (w == 0) {
    double v[4];
    int ix[4];
#pragma unroll
    for (int j = 0; j < 4; j++) { v[j] = sc[lane + j * 64]; ix[j] = lane + j * 64; }
    for (int kk = 0; kk < CK; kk++) {
      double v1 = v[0]; int i1 = ix[0];
#pragma unroll
      for (int j = 1; j < 4; j++)
        if (v[j] > v1) { v1 = v[j]; i1 = ix[j]; }
#pragma unroll
      for (int off = 32; off > 0; off >>= 1) {
        double ov = __shfl_down(v1, off);
        int oi = __shfl_down(i1, off);
        if (ov > v1) { v1 = ov; i1 = oi; }
      }
      i1 = __shfl(i1, 0);
      if (lane == 0) coarse[(size_t)t * CK + kk] = ci[i1];
#pragma unroll
      for (int j = 0; j < 4; j++)
        if (i1 == ix[j]) v[j] = -1e300;
    }
  }
}

// ---------------------------------------------------------------------------
// K4a (r16 exact): query = x @ W_enc, 8 tokens/block.
// ---------------------------------------------------------------------------
__global__ __launch_bounds__(256) void k_query8(const float* __restrict__ x,
                                                const float* __restrict__ Wenc,
                                                float* __restrict__ q) {
  __shared__ __align__(16) float xs8[8 * DIM];  // 32 KB
  __shared__ float pq[2][8][RNK];               // 8 KB
  const int t0 = blockIdx.x * 8, tid = threadIdx.x;
  for (int i = tid; i < 2048; i += 256)
    reinterpret_cast<float4*>(xs8)[i] =
        reinterpret_cast<const float4*>(x + (size_t)t0 * DIM)[i];
  __syncthreads();
  const int j = tid & 127, g = tid >> 7;
  float s[8] = {0.f, 0.f, 0.f, 0.f, 0.f, 0.f, 0.f, 0.f};
  for (int d = g * 512; d < g * 512 + 512; ++d) {
    const float wv = Wenc[(size_t)d * RNK + j];
#pragma unroll
    for (int tok = 0; tok < 8; ++tok)
      s[tok] = fmaf(xs8[tok * DIM + d], wv, s[tok]);
  }
#pragma unroll
  for (int tok = 0; tok < 8; ++tok) pq[g][tok][j] = s[tok];
  __syncthreads();
  for (int i = tid; i < 8 * RNK; i += 256) {
    const int tok = i >> 7, jj = i & 127;
    q[(size_t)(t0 + tok) * RNK + jj] = pq[0][tok][jj] + pq[1][tok][jj];
  }
}

// ---------------------------------------------------------------------------
// K4b (r16 exact): fine scores vs 20 candidates, top-10, softmax, V blend.
// ---------------------------------------------------------------------------
__global__ __launch_bounds__(256) void k_fine(const float* __restrict__ q,
                                              const float* __restrict__ Kall,
                                              const float* __restrict__ Vall,
                                              const int* __restrict__ coarse,
                                              float* __restrict__ out) {
  __shared__ float qs[RNK];
  __shared__ float fsc[CK];
  __shared__ int gix[CK];
  __shared__ float wts[FK];
  __shared__ int fidx[FK];
  const int t = blockIdx.x, tid = threadIdx.x;
  const int lane = tid & 63, w = tid >> 6;
  if (tid < RNK) qs[tid] = q[(size_t)t * RNK + tid];
  if (tid < CK) gix[tid] = coarse[(size_t)t * CK + tid];
  __syncthreads();
  for (int c = w; c < CK; c += 4) {
    const float* kr = Kall + (size_t)gix[c] * RNK;
    float s = 0.f;
    s = fmaf(qs[lane], kr[lane], s);
    s = fmaf(qs[lane + 64], kr[lane + 64], s);
#pragma unroll
    for (int off = 32; off > 0; off >>= 1) s += __shfl_down(s, off);
    if (lane == 0) fsc[c] = s * 0.08838834764831843f;  // 1/sqrt(128)
  }
  __syncthreads();
  if (w == 0) {
    float vv = (lane < CK) ? fsc[lane] : -3e38f;
    float myv = -3e38f; int myp = 0;
    for (int kk = 0; kk < FK; kk++) {
      float v1 = vv; int p1 = lane;
#pragma unroll
      for (int off = 32; off > 0; off >>= 1) {
        float ov = __shfl_down(v1, off);
        int op = __shfl_down(p1, off);
        if (ov > v1) { v1 = ov; p1 = op; }
      }
      v1 = __shfl(v1, 0); p1 = __shfl(p1, 0);
      if (lane == kk) { myv = v1; myp = p1; }
      if (lane == p1) vv = -3e38f;
    }
    float sv = (lane < FK) ? myv : -3e38f;
    float mx = sv;
#pragma unroll
    for (int off = 8; off > 0; off >>= 1) mx = fmaxf(mx, __shfl_xor(mx, off, 16));
    float e = (lane < FK) ? expf(sv - mx) : 0.f;
    float se = e;
#pragma unroll
    for (int off = 8; off > 0; off >>= 1) se += __shfl_xor(se, off, 16);
    if (lane < FK) { wts[lane] = e / se; fidx[lane] = gix[myp]; }
  }
  __syncthreads();
  float4 a = make_float4(0.f, 0.f, 0.f, 0.f);
#pragma unroll
  for (int f = 0; f < FK; f++) {
    const float wt = wts[f];
    const float4 v = *reinterpret_cast<const float4*>(&Vall[(size_t)fidx[f] * DIM + tid * 4]);
    a.x = fmaf(wt, v.x, a.x);
    a.y = fmaf(wt, v.y, a.y);
    a.z = fmaf(wt, v.z, a.z);
    a.w = fmaf(wt, v.w, a.w);
  }
  *reinterpret_cast<float4*>(&out[(size_t)t * DIM + tid * 4]) = a;
}

// ---------------------------------------------------------------------------

extern "C" void kernel_launch(void* const* d_in, const int* in_sizes, int n_in,
                              void* d_out, int out_size, void* d_ws, size_t ws_size,
                              hipStream_t stream) {
  const float* x = (const float*)d_in[0];      // [4096][1024]
  const float* Wr = (const float*)d_in[1];     // [1024][65536]
  const float* Wenc = (const float*)d_in[2];   // [1024][128]
  const float* Kall = (const float*)d_in[3];   // [65536][128]
  const float* Vall = (const float*)d_in[4];   // [65536][1024]
  float* out = (float*)d_out;                  // [4096][1024]

  char* ws = (char*)d_ws;
  constexpr size_t OFF_WT = 0;                  // fp32 W^T    256 MB (live until pickscore)
  constexpr size_t OFF_WTB = 268435456;         // bf16 W^T    128 MB (dead after gemm)
  constexpr size_t OFF_XB = 402653184;          // bf16 x        8 MB (dead after gemm)
  constexpr size_t OFF_TTOP = 411041792;        // top-8 table  64 MB
  float* WT = (float*)(ws + OFF_WT);
  unsigned short* WTb = (unsigned short*)(ws + OFF_WTB);
  unsigned short* xb = (unsigned short*)(ws + OFF_XB);
  unsigned* Ttop = (unsigned*)(ws + OFF_TTOP);
  int* coarse = (int*)(ws + OFF_XB);            // 320 KB, aliases dead xb region
  float* q = (float*)(ws + OFF_XB + 4194304);   // 2 MB, aliases dead xb region

  k_prep<<<69632, 256, 0, stream>>>(Wr, WT, WTb, x, xb);
  k_gemm<<<8192, 512, 0, stream>>>(xb, WTb, Ttop);
  k_pickscore<<<4096, 256, 0, stream>>>(Ttop, x, WT, coarse);
  k_query8<<<512, 256, 0, stream>>>(x, Wenc, q);
  k_fine<<<4096, 256, 0, stream>>>(q, Kall, Vall, coarse, out);
}